// Round 17
// baseline (164.986 us; speedup 1.0000x reference)
//
// T5 encoder layer — round 17: attn STAGE hoisted before TILE (issue-early,
// T14 ordering; write-after-read safe past the top barrier, vmcnt unchanged).
// Everything else frozen from round 16 (164.8us best).
#include <hip/hip_runtime.h>

typedef __bf16 bf16_t;
typedef __bf16 bf16x8 __attribute__((ext_vector_type(8)));
typedef __bf16 bf16x4 __attribute__((ext_vector_type(4)));
typedef float  f32x4  __attribute__((ext_vector_type(4)));

#define MFMA_BF16 __builtin_amdgcn_mfma_f32_16x16x32_bf16

template <int N> __device__ __forceinline__ void wait_vmcnt() {
  if constexpr (N == 0)      asm volatile("s_waitcnt vmcnt(0)" ::: "memory");
  else if constexpr (N == 2) asm volatile("s_waitcnt vmcnt(2)" ::: "memory");
  else if constexpr (N == 4) asm volatile("s_waitcnt vmcnt(4)" ::: "memory");
  else if constexpr (N == 6) asm volatile("s_waitcnt vmcnt(6)" ::: "memory");
  else if constexpr (N == 8) asm volatile("s_waitcnt vmcnt(8)" ::: "memory");
}

__device__ __forceinline__ void gload_lds16(const void* g, void* l) {
  __builtin_amdgcn_global_load_lds((const __attribute__((address_space(1))) void*)g,
                                   (__attribute__((address_space(3))) void*)l,
                                   16, 0, 0);
}

// swizzled fragment read from a [rows][64-bf16] LDS tile (128B rows).
__device__ __forceinline__ bf16x8 lds_frag(const bf16_t* base, int row, int c2) {
  return *(const bf16x8*)((const char*)base + ((((row) << 7) + c2) ^ ((row & 7) << 4)));
}

// ---------------- merged prep: cvt(x) + 6 weight transposes + bias table + cat2 ----------------
__global__ __launch_bounds__(256) void prep_k(const float* __restrict__ x, bf16_t* __restrict__ xb,
                                              const float* __restrict__ Wq, const float* __restrict__ Wk,
                                              const float* __restrict__ Wv, const float* __restrict__ Wo,
                                              const float* __restrict__ W1, const float* __restrict__ W2,
                                              bf16_t* __restrict__ WqkT, bf16_t* __restrict__ WvT,
                                              bf16_t* __restrict__ WoT, bf16_t* __restrict__ W1T,
                                              bf16_t* __restrict__ W2T,
                                              const float* __restrict__ relb, float* __restrict__ btab,
                                              const float* __restrict__ bq, const float* __restrict__ bk,
                                              float* __restrict__ bqk) {
  __shared__ float tsh[64][65];
  const int bid = blockIdx.x, tid = threadIdx.x;
  if (bid < 4096) {
    int i = bid * 256 + tid;
    float4 v = ((const float4*)x)[i];
    bf16x4 o = { (bf16_t)v.x, (bf16_t)v.y, (bf16_t)v.z, (bf16_t)v.w };
    ((bf16x4*)xb)[i] = o;
  } else if (bid < 4864) {
    int jid = bid - 4096;
    const float* src; bf16_t* dst; int K, N, n0, k0;
    if (jid < 256) {
      int wsel = jid >> 6, t = jid & 63;
      src = wsel == 0 ? Wq : wsel == 1 ? Wk : wsel == 2 ? Wv : Wo;
      dst = wsel == 0 ? WqkT : wsel == 1 ? (WqkT + 512 * 512) : wsel == 2 ? WvT : WoT;
      K = 512; N = 512; n0 = (t >> 3) * 64; k0 = (t & 7) * 64;
    } else if (jid < 512) {
      int t = jid - 256; src = W1; dst = W1T; K = 512; N = 2048;
      n0 = (t >> 3) * 64; k0 = (t & 7) * 64;
    } else {
      int t = jid - 512; src = W2; dst = W2T; K = 2048; N = 512;
      n0 = (t & 7) * 64; k0 = (t >> 3) * 64;
    }
    int tx = tid & 63, g = tid >> 6;
#pragma unroll
    for (int i = g; i < 64; i += 4) tsh[i][tx] = src[(size_t)(k0 + i) * N + n0 + tx];
    __syncthreads();
#pragma unroll
    for (int i = g; i < 64; i += 4)
      dst[(size_t)(n0 + i) * K + k0 + tx] = (bf16_t)tsh[tx][i];
  } else if (bid < 4992) {
    const float SCL = 0.125f * 1.44269504088896f;
    int i = (bid - 4864) * 256 + tid;
    if (i < 8 * 4095) {
      int h = i / 4095;
      int r = (i % 4095) - 2047;
      int ret = (r < 0) ? 16 : 0;
      int n = (r < 0) ? -r : r;
      int b;
      if (n < 8) b = n;
      else {
        float v = logf((float)n / 8.0f) / logf(16.0f) * 8.0f;
        int vi = 8 + (int)v;
        b = vi < 15 ? vi : 15;
      }
      btab[i] = relb[h * 32 + ret + b] * SCL;
    }
  } else {
    int i = (bid - 4992) * 256 + tid;
    if (i < 1024) bqk[i] = (i < 512) ? bq[i] : bk[i - 512];
  }
}

// ---------------- bf16 MFMA GEMM: T2 swizzle + T1 XCD swizzle, NW = WR*WC waves ----------------
// DBUF=1: 2-buffer, ONE barrier per K-step: barrier; STG(t+1); vmcnt(LPS); CMP(t).
template <int BM, int BN, int WR, int WC, int NXB, int OUT_F32, int RELU, int BIASROW, int DBUF>
__global__ __launch_bounds__(WR * WC * 64) void gemm_k(const bf16_t* __restrict__ A,
                                                       const bf16_t* __restrict__ Bt,
                                                       const float* __restrict__ bias,
                                                       void* __restrict__ outp,
                                                       int M, int N, int K) {
  constexpr int NW = WR * WC;
  constexpr int AI = BM / WR / 16;
  constexpr int BJ = BN / WC / 16;
  constexpr int LPA = BM / (NW * 8);
  constexpr int LPB = BN / (NW * 8);
  constexpr int LPS = LPA + LPB;
  constexpr int MCH = NXB / 8;               // M-blocks per XCD chunk
  __shared__ __align__(16) bf16_t As[(DBUF + 1) * BM * 64];
  __shared__ __align__(16) bf16_t Bs[(DBUF + 1) * BN * 64];
  const int tid = threadIdx.x;
  const int lane = tid & 63, wid = tid >> 6;
  const int bid = blockIdx.x;
  const int xcd = bid & 7, li = bid >> 3;
  const int m0 = (xcd * MCH + li % MCH) * BM;
  const int n0 = (li / MCH) * BN;
  const int wr = wid / WC, wc = wid % WC;
  const int l15 = lane & 15, lg = lane >> 4;
  const int srow = lane >> 3;
  const int scolx = ((lane & 7) ^ srow) * 8;   // pre-swizzled source column

  f32x4 acc[AI][BJ];
#pragma unroll
  for (int i = 0; i < AI; i++)
#pragma unroll
    for (int j = 0; j < BJ; j++) acc[i][j] = f32x4{0.f, 0.f, 0.f, 0.f};

  const bf16_t* Ag = A + (size_t)(m0 + wid * (BM / NW) + srow) * K + scolx;
  const bf16_t* Bg = Bt + (size_t)(n0 + wid * (BN / NW) + srow) * K + scolx;

  auto STG = [&](int buf, int k0) {
#pragma unroll
    for (int i = 0; i < LPA; i++)
      gload_lds16(Ag + (size_t)i * 8 * K + k0,
                  As + buf * (BM * 64) + wid * (BM / NW) * 64 + i * 8 * 64);
#pragma unroll
    for (int i = 0; i < LPB; i++)
      gload_lds16(Bg + (size_t)i * 8 * K + k0,
                  Bs + buf * (BN * 64) + wid * (BN / NW) * 64 + i * 8 * 64);
  };

  auto CMP = [&](int buf) {
    const bf16_t* AsB = As + buf * (BM * 64);
    const bf16_t* BsB = Bs + buf * (BN * 64);
#pragma unroll
    for (int ks = 0; ks < 2; ks++) {
      const int c2 = ks * 64 + lg * 16;
      bf16x8 af[AI], bfv[BJ];
#pragma unroll
      for (int i = 0; i < AI; i++)
        af[i] = lds_frag(AsB, wr * (BM / WR) + i * 16 + l15, c2);
#pragma unroll
      for (int j = 0; j < BJ; j++)
        bfv[j] = lds_frag(BsB, wc * (BN / WC) + j * 16 + l15, c2);
#pragma unroll
      for (int i = 0; i < AI; i++)
#pragma unroll
        for (int j = 0; j < BJ; j++)
          acc[i][j] = MFMA_BF16(af[i], bfv[j], acc[i][j], 0, 0, 0);
    }
  };

  if constexpr (DBUF) {
    STG(0, 0);
    const int NK = K >> 6;
#pragma unroll 2
    for (int t = 0; t < NK; t++) {
      const int buf = t & 1;
      __syncthreads();                 // CMP(t-1) reads of buf^1 done before overwrite
      if (t + 1 < NK) {
        STG(buf ^ 1, (t + 1) << 6);
        wait_vmcnt<LPS>();             // tile t's loads landed (t+1's still in flight)
      } else {
        wait_vmcnt<0>();
      }
      CMP(buf);
    }
  } else {
    for (int k0 = 0; k0 < K; k0 += 64) {
      __syncthreads();
      STG(0, k0);
      wait_vmcnt<0>();
      __syncthreads();
      CMP(0);
    }
  }

  const int r0 = m0 + wr * (BM / WR) + (lg << 2);
  const int c0 = n0 + wc * (BN / WC) + l15;
#pragma unroll
  for (int j = 0; j < BJ; j++) {
    const int col = c0 + j * 16;
    const float bvc = BIASROW ? 0.f : bias[col];
#pragma unroll
    for (int i = 0; i < AI; i++) {
      const int row = r0 + i * 16;
#pragma unroll
      for (int r = 0; r < 4; r++) {
        float v = acc[i][j][r] + (BIASROW ? bias[row + r] : bvc);
        if (RELU) v = fmaxf(v, 0.f);
        if (OUT_F32) ((float*)outp)[(size_t)(row + r) * N + col] = v;
        else         ((bf16_t*)outp)[(size_t)(row + r) * N + col] = (bf16_t)v;
      }
    }
  }
}

// ---------------- flash attention: 8 waves, QBLK=128, static softmax ----------------
// 3-buffer K/V, 1 barrier/tile, counted vmcnt(2), hw exp2, STAGE issued early.
__global__ __launch_bounds__(512) void attn_k(const bf16_t* __restrict__ Q,
                                              const bf16_t* __restrict__ Kp,
                                              const bf16_t* __restrict__ Vt,
                                              const float* __restrict__ btabS,
                                              const float* __restrict__ relb,
                                              bf16_t* __restrict__ ctx) {
  __shared__ __align__(16) bf16_t Ks[3][64 * 64];
  __shared__ __align__(16) bf16_t Vs[3][64 * 64];
  __shared__ __align__(16) bf16_t Ps[8][16 * 64];
  const int tid = threadIdx.x;
  const int lane = tid & 63, wid = tid >> 6;
  const int bid = blockIdx.x;
  const int xcd = bid & 7, tt = bid >> 3;
  const int qb = tt & 15, bh = (tt >> 4) * 8 + xcd;
  const int q0 = qb * 128;
  const int bb = bh >> 3, h = bh & 7;
  const size_t qkbase = (size_t)bb * 2048 * 1024;
  const size_t cbase = (size_t)bb * 2048 * 512;
  const int hc = h * 64;
  const int l15 = lane & 15, lg = lane >> 4;
  const int srow = lane >> 3;
  const int scolx = ((lane & 7) ^ srow) * 8;

  const bf16_t* qp = Q + qkbase + (size_t)(q0 + wid * 16 + l15) * 1024 + hc + lg * 8;
  bf16x8 qf0 = *(const bf16x8*)qp;
  bf16x8 qf1 = *(const bf16x8*)(qp + 32);

  const float SCL = 0.125f * 1.44269504088896f;
  const float* bt = btabS + (size_t)h * 4095 + 2047;
  const float cbp = relb[h * 32 + 15] * SCL;
  const float cbn = relb[h * 32 + 31] * SCL;

  float lrow = 0.f;                         // lane-local partial row sum
  f32x4 acc[4];
#pragma unroll
  for (int dn = 0; dn < 4; dn++) acc[dn] = f32x4{0.f, 0.f, 0.f, 0.f};
  char* pw = (char*)&Ps[wid][0];
  const int rq = q0 + wid * 16 + l15;

  const bf16_t* kg = Kp + qkbase + (size_t)(wid * 8 + srow) * 1024 + hc + scolx;
  const bf16_t* vg = Vt + (size_t)(hc + wid * 8 + srow) * 8192 + bb * 2048 + scolx;

#define STAGE(bufp, kv0)                                              \
  do {                                                                \
    gload_lds16(kg + (size_t)(kv0) * 1024, &Ks[bufp][wid * 8 * 64]);  \
    gload_lds16(vg + (kv0), &Vs[bufp][wid * 8 * 64]);                 \
  } while (0)

  auto TILE = [&](int t, int buf) {
    const int kv0 = t * 64;
    const bf16_t* KsB = &Ks[buf][0];
    const bf16_t* VsB = &Vs[buf][0];

    f32x4 s[4];
#pragma unroll
    for (int n = 0; n < 4; n++) s[n] = f32x4{0.f, 0.f, 0.f, 0.f};
    __builtin_amdgcn_s_setprio(1);
#pragma unroll
    for (int ks = 0; ks < 2; ks++) {
      bf16x8 qf = ks ? qf1 : qf0;
      const int c2 = ks * 64 + lg * 16;
#pragma unroll
      for (int n = 0; n < 4; n++) {
        bf16x8 kf = lds_frag(KsB, n * 16 + l15, c2);
        s[n] = MFMA_BF16(kf, qf, s[n], 0, 0, 0);
      }
    }
    __builtin_amdgcn_s_setprio(0);

    float lg2[4][4];
    const bool farp = (q0 - kv0) >= 192;   // min rel = q0-kv0-63 >= 129
    const bool farn = (kv0 - q0) >= 256;   // max rel = q0+127-kv0 <= -129
    if (farp || farn) {
      const float cb = farp ? cbp : cbn;
#pragma unroll
      for (int n = 0; n < 4; n++)
#pragma unroll
        for (int r = 0; r < 4; r++) lg2[n][r] = s[n][r] * SCL + cb;
    } else {
#pragma unroll
      for (int n = 0; n < 4; n++) {
        const float* btn = bt + (rq - kv0 - n * 16 - lg * 4);
#pragma unroll
        for (int r = 0; r < 4; r++) lg2[n][r] = s[n][r] * SCL + btn[-r];
      }
    }

#pragma unroll
    for (int n = 0; n < 4; n++) {
      float p0 = __builtin_amdgcn_exp2f(lg2[n][0]);
      float p1 = __builtin_amdgcn_exp2f(lg2[n][1]);
      float p2 = __builtin_amdgcn_exp2f(lg2[n][2]);
      float p3 = __builtin_amdgcn_exp2f(lg2[n][3]);
      lrow += (p0 + p1) + (p2 + p3);
      unsigned w0, w1;
      asm("v_cvt_pk_bf16_f32 %0, %1, %2" : "=v"(w0) : "v"(p0), "v"(p1));
      asm("v_cvt_pk_bf16_f32 %0, %1, %2" : "=v"(w1) : "v"(p2), "v"(p3));
      uint2 wv = {w0, w1};
      *(uint2*)(pw + (((l15 << 7) + n * 32 + (lg >> 1) * 16 + (lg & 1) * 8)
                      ^ ((l15 & 7) << 4))) = wv;
    }

    asm volatile("s_waitcnt lgkmcnt(0)" ::: "memory");
    __builtin_amdgcn_sched_barrier(0);

    __builtin_amdgcn_s_setprio(1);
#pragma unroll
    for (int ks = 0; ks < 2; ks++) {
      const int c2 = ks * 64 + lg * 16;
      bf16x8 pa = *(const bf16x8*)(pw + (((l15 << 7) + ks * 64 + (lg >> 1) * 32 + (lg & 1) * 16)
                                         ^ ((l15 & 7) << 4)));
#pragma unroll
      for (int dn = 0; dn < 4; dn++) {
        bf16x8 vf = lds_frag(VsB, dn * 16 + l15, c2);
        acc[dn] = MFMA_BF16(pa, vf, acc[dn], 0, 0, 0);
      }
    }
    __builtin_amdgcn_s_setprio(0);
  };

  // prologue: 2 tiles in flight (depth-2); 3-buffer rotation, 1 barrier/tile.
  // STAGE issued BEFORE TILE: safe (all waves past barrier finished reading
  // buf(t+2)=buf(t-1)); vmcnt(2) semantics unchanged (FIFO).
  STAGE(0, 0);
  STAGE(1, 64);

  int cur = 0, nx2 = 2;
  for (int t = 0; t < 31; t++) {
    wait_vmcnt<2>();
    __syncthreads();
    if (t < 30) STAGE(nx2, (t + 2) * 64);
    TILE(t, cur);
    cur = (cur == 2) ? 0 : cur + 1;
    nx2 = (nx2 == 2) ? 0 : nx2 + 1;
  }
  wait_vmcnt<0>();
  __syncthreads();
  TILE(31, cur);
#undef STAGE

  // reduce lane-local partial sums once
  lrow += __shfl_xor(lrow, 16, 64);
  lrow += __shfl_xor(lrow, 32, 64);

  float li0 = __shfl(lrow, (lg << 2) + 0, 64);
  float li1 = __shfl(lrow, (lg << 2) + 1, 64);
  float li2 = __shfl(lrow, (lg << 2) + 2, 64);
  float li3 = __shfl(lrow, (lg << 2) + 3, 64);
  float inv[4] = {1.f / li0, 1.f / li1, 1.f / li2, 1.f / li3};
  const int qr0 = q0 + wid * 16 + (lg << 2);
#pragma unroll
  for (int dn = 0; dn < 4; dn++)
#pragma unroll
    for (int r = 0; r < 4; r++)
      ctx[cbase + (size_t)(qr0 + r) * 512 + hc + dn * 16 + l15] = (bf16_t)(acc[dn][r] * inv[r]);
}

// ---------------- residual + LayerNorm (bf16 inputs; optional f32/bf16 outputs) ----------------
__global__ __launch_bounds__(256) void lnres_k(const bf16_t* __restrict__ a,
                                               const bf16_t* __restrict__ bsrc,
                                               const float* __restrict__ sc,
                                               const float* __restrict__ bi,
                                               float* __restrict__ outf,
                                               bf16_t* __restrict__ outb) {
  int row = blockIdx.x * 4 + (threadIdx.x >> 6);
  int lane = threadIdx.x & 63;
  size_t base = (size_t)row * 512 + lane * 8;
  bf16x8 av8 = *(const bf16x8*)(a + base);
  bf16x8 bv8 = *(const bf16x8*)(bsrc + base);
  float v[8];
#pragma unroll
  for (int j = 0; j < 8; j++) v[j] = (float)av8[j] + (float)bv8[j];
  float s1 = 0.f, s2 = 0.f;
#pragma unroll
  for (int j = 0; j < 8; j++) { s1 += v[j]; s2 += v[j] * v[j]; }
#pragma unroll
  for (int off = 1; off < 64; off <<= 1) {
    s1 += __shfl_xor(s1, off, 64);
    s2 += __shfl_xor(s2, off, 64);
  }
  float mu = s1 * (1.f / 512.f);
  float var = s2 * (1.f / 512.f) - mu * mu;
  float rstd = rsqrtf(var + 1e-6f);
  int c = lane * 8;
  float4 sc0 = *(const float4*)(sc + c), sc1 = *(const float4*)(sc + c + 4);
  float4 bi0 = *(const float4*)(bi + c), bi1 = *(const float4*)(bi + c + 4);
  float scv[8] = {sc0.x, sc0.y, sc0.z, sc0.w, sc1.x, sc1.y, sc1.z, sc1.w};
  float biv[8] = {bi0.x, bi0.y, bi0.z, bi0.w, bi1.x, bi1.y, bi1.z, bi1.w};
  float o[8];
#pragma unroll
  for (int j = 0; j < 8; j++) o[j] = (v[j] - mu) * rstd * scv[j] + biv[j];
  if (outf) {
    *(float4*)(outf + base) = make_float4(o[0], o[1], o[2], o[3]);
    *(float4*)(outf + base + 4) = make_float4(o[4], o[5], o[6], o[7]);
  }
  if (outb) {
    bf16x8 ob = {(bf16_t)o[0], (bf16_t)o[1], (bf16_t)o[2], (bf16_t)o[3],
                 (bf16_t)o[4], (bf16_t)o[5], (bf16_t)o[6], (bf16_t)o[7]};
    *(bf16x8*)(outb + base) = ob;
  }
}

// ---------------- host launcher ----------------
extern "C" void kernel_launch(void* const* d_in, const int* in_sizes, int n_in,
                              void* d_out, int out_size, void* d_ws, size_t ws_size,
                              hipStream_t stream) {
  const float* x    = (const float*)d_in[0];
  const float* Wq   = (const float*)d_in[1];
  const float* bq   = (const float*)d_in[2];
  const float* Wk   = (const float*)d_in[3];
  const float* bk   = (const float*)d_in[4];
  const float* Wv   = (const float*)d_in[5];
  const float* bv   = (const float*)d_in[6];
  const float* Wo   = (const float*)d_in[7];
  const float* bo   = (const float*)d_in[8];
  const float* relb = (const float*)d_in[9];
  const float* W1   = (const float*)d_in[10];
  const float* b1   = (const float*)d_in[11];
  const float* W2   = (const float*)d_in[12];
  const float* b2   = (const float*)d_in[13];
  const float* ln1s = (const float*)d_in[14];
  const float* ln1b = (const float*)d_in[15];
  const float* ln2s = (const float*)d_in[16];
  const float* ln2b = (const float*)d_in[17];

  char* w = (char*)d_ws;
  bf16_t* xb    = (bf16_t*)(w + 0);          //  8 MB [8192][512]; read until lnres1
  bf16_t* qk    = (bf16_t*)(w + 8388608);    // 16 MB [8192][1024]; dead after attn
  bf16_t* tmpb  = (bf16_t*)(w + 8388608);    //  8 MB (Wo out bf16; overlays dead qk)
  bf16_t* vtg   = (bf16_t*)(w + 25165824);   //  8 MB [512][8192]; dead after attn
  bf16_t* ctxb  = (bf16_t*)(w + 33554432);   //  8 MB; dead after Wo
  bf16_t* tmpb2 = (bf16_t*)(w + 33554432);   //  8 MB (FFN2 out bf16; overlays dead ctxb)
  bf16_t* x1b   = (bf16_t*)(w + 50331648);   //  8 MB (LN1 out bf16)
  bf16_t* WqkT  = (bf16_t*)(w + 58720256);   //  1 MB [1024][512]
  bf16_t* WvT   = (bf16_t*)(w + 59768832);   // 0.5 MB
  bf16_t* WoT   = (bf16_t*)(w + 60293120);   // 0.5 MB
  bf16_t* W1T   = (bf16_t*)(w + 60817408);   //  2 MB [2048][512]
  bf16_t* W2T   = (bf16_t*)(w + 62914560);   //  2 MB [512][2048]
  float*  btab  = (float*)(w + 65011712);    // 128 KB
  float*  bqk   = (float*)(w + 65273856);    //  4 KB
  bf16_t* ffh   = (bf16_t*)(w + 67108864);   // 32 MB [8192][2048]

  // single merged prep launch
  prep_k<<<4996, 256, 0, stream>>>(x, xb, Wq, Wk, Wv, Wo, W1, W2,
                                   WqkT, WvT, WoT, W1T, W2T,
                                   relb, btab, bq, bk, bqk);

  // QK projection [8192][1024]: 128x128, 4 waves, dbuf-1barrier, XCD-swizzled
  gemm_k<128, 128, 2, 2, 64, 0, 0, 0, 1><<<512, 256, 0, stream>>>(xb, WqkT, bqk, qk, 8192, 1024, 512);
  // V^T projection: 64x128, dbuf-1barrier, XCD-swizzled
  gemm_k<64, 128, 1, 4, 8, 0, 0, 1, 1><<<512, 256, 0, stream>>>(WvT, xb, bv, vtg, 512, 8192, 512);

  // attention: 8 waves, QBLK=128, grid 512 XCD-swizzled, static softmax, hw exp2
  attn_k<<<512, 512, 0, stream>>>(qk, qk + 512, vtg, btab, relb, ctxb);

  // Wo (bf16 out): 64x128 dbuf-1barrier
  gemm_k<64, 128, 1, 4, 128, 0, 0, 0, 1><<<512, 256, 0, stream>>>(ctxb, WoT, bo, tmpb, 8192, 512, 512);
  lnres_k<<<2048, 256, 0, stream>>>(xb, tmpb, ln1s, ln1b, (float*)nullptr, x1b);

  // FFN1: 128x128 dbuf-1barrier (r16 win)
  gemm_k<128, 128, 2, 2, 64, 0, 1, 0, 1><<<1024, 256, 0, stream>>>(x1b, W1T, b1, ffh, 8192, 2048, 512);
  // FFN2: 64x128 dbuf-1barrier
  gemm_k<64, 128, 1, 4, 128, 0, 0, 0, 1><<<512, 256, 0, stream>>>(ffh, W2T, b2, tmpb2, 8192, 512, 2048);
  lnres_k<<<2048, 256, 0, stream>>>(x1b, tmpb2, ln2s, ln2b, (float*)d_out, (bf16_t*)nullptr);
}

// Round 18
// 164.472 us; speedup vs baseline: 1.0031x; 1.0031x over previous
//
// T5 encoder layer — FINAL (round-16 measured-best, 164.8us; r17 hoist reverted
// as neutral). Structure: bf16 MFMA everywhere; fused-prep; QK/Vt/Wo/FFN1/FFN2
// GEMMs with T2 LDS-XOR-swizzle + T1 XCD-swizzle + dbuf-1-barrier counted-vmcnt;
// flash attn 8-wave QBLK=128 swapped-QK static-softmax (hw exp2) 3-buffer
// 1-barrier pipeline; bf16 residual chain. 368us (r1) -> 164.8us.
#include <hip/hip_runtime.h>

typedef __bf16 bf16_t;
typedef __bf16 bf16x8 __attribute__((ext_vector_type(8)));
typedef __bf16 bf16x4 __attribute__((ext_vector_type(4)));
typedef float  f32x4  __attribute__((ext_vector_type(4)));

#define MFMA_BF16 __builtin_amdgcn_mfma_f32_16x16x32_bf16

template <int N> __device__ __forceinline__ void wait_vmcnt() {
  if constexpr (N == 0)      asm volatile("s_waitcnt vmcnt(0)" ::: "memory");
  else if constexpr (N == 2) asm volatile("s_waitcnt vmcnt(2)" ::: "memory");
  else if constexpr (N == 4) asm volatile("s_waitcnt vmcnt(4)" ::: "memory");
  else if constexpr (N == 6) asm volatile("s_waitcnt vmcnt(6)" ::: "memory");
  else if constexpr (N == 8) asm volatile("s_waitcnt vmcnt(8)" ::: "memory");
}

__device__ __forceinline__ void gload_lds16(const void* g, void* l) {
  __builtin_amdgcn_global_load_lds((const __attribute__((address_space(1))) void*)g,
                                   (__attribute__((address_space(3))) void*)l,
                                   16, 0, 0);
}

// swizzled fragment read from a [rows][64-bf16] LDS tile (128B rows).
__device__ __forceinline__ bf16x8 lds_frag(const bf16_t* base, int row, int c2) {
  return *(const bf16x8*)((const char*)base + ((((row) << 7) + c2) ^ ((row & 7) << 4)));
}

// ---------------- merged prep: cvt(x) + 6 weight transposes + bias table + cat2 ----------------
__global__ __launch_bounds__(256) void prep_k(const float* __restrict__ x, bf16_t* __restrict__ xb,
                                              const float* __restrict__ Wq, const float* __restrict__ Wk,
                                              const float* __restrict__ Wv, const float* __restrict__ Wo,
                                              const float* __restrict__ W1, const float* __restrict__ W2,
                                              bf16_t* __restrict__ WqkT, bf16_t* __restrict__ WvT,
                                              bf16_t* __restrict__ WoT, bf16_t* __restrict__ W1T,
                                              bf16_t* __restrict__ W2T,
                                              const float* __restrict__ relb, float* __restrict__ btab,
                                              const float* __restrict__ bq, const float* __restrict__ bk,
                                              float* __restrict__ bqk) {
  __shared__ float tsh[64][65];
  const int bid = blockIdx.x, tid = threadIdx.x;
  if (bid < 4096) {
    int i = bid * 256 + tid;
    float4 v = ((const float4*)x)[i];
    bf16x4 o = { (bf16_t)v.x, (bf16_t)v.y, (bf16_t)v.z, (bf16_t)v.w };
    ((bf16x4*)xb)[i] = o;
  } else if (bid < 4864) {
    int jid = bid - 4096;
    const float* src; bf16_t* dst; int K, N, n0, k0;
    if (jid < 256) {
      int wsel = jid >> 6, t = jid & 63;
      src = wsel == 0 ? Wq : wsel == 1 ? Wk : wsel == 2 ? Wv : Wo;
      dst = wsel == 0 ? WqkT : wsel == 1 ? (WqkT + 512 * 512) : wsel == 2 ? WvT : WoT;
      K = 512; N = 512; n0 = (t >> 3) * 64; k0 = (t & 7) * 64;
    } else if (jid < 512) {
      int t = jid - 256; src = W1; dst = W1T; K = 512; N = 2048;
      n0 = (t >> 3) * 64; k0 = (t & 7) * 64;
    } else {
      int t = jid - 512; src = W2; dst = W2T; K = 2048; N = 512;
      n0 = (t & 7) * 64; k0 = (t >> 3) * 64;
    }
    int tx = tid & 63, g = tid >> 6;
#pragma unroll
    for (int i = g; i < 64; i += 4) tsh[i][tx] = src[(size_t)(k0 + i) * N + n0 + tx];
    __syncthreads();
#pragma unroll
    for (int i = g; i < 64; i += 4)
      dst[(size_t)(n0 + i) * K + k0 + tx] = (bf16_t)tsh[tx][i];
  } else if (bid < 4992) {
    const float SCL = 0.125f * 1.44269504088896f;
    int i = (bid - 4864) * 256 + tid;
    if (i < 8 * 4095) {
      int h = i / 4095;
      int r = (i % 4095) - 2047;
      int ret = (r < 0) ? 16 : 0;
      int n = (r < 0) ? -r : r;
      int b;
      if (n < 8) b = n;
      else {
        float v = logf((float)n / 8.0f) / logf(16.0f) * 8.0f;
        int vi = 8 + (int)v;
        b = vi < 15 ? vi : 15;
      }
      btab[i] = relb[h * 32 + ret + b] * SCL;
    }
  } else {
    int i = (bid - 4992) * 256 + tid;
    if (i < 1024) bqk[i] = (i < 512) ? bq[i] : bk[i - 512];
  }
}

// ---------------- bf16 MFMA GEMM: T2 swizzle + T1 XCD swizzle, NW = WR*WC waves ----------------
// DBUF=1: 2-buffer, ONE barrier per K-step: barrier; STG(t+1); vmcnt(LPS); CMP(t).
template <int BM, int BN, int WR, int WC, int NXB, int OUT_F32, int RELU, int BIASROW, int DBUF>
__global__ __launch_bounds__(WR * WC * 64) void gemm_k(const bf16_t* __restrict__ A,
                                                       const bf16_t* __restrict__ Bt,
                                                       const float* __restrict__ bias,
                                                       void* __restrict__ outp,
                                                       int M, int N, int K) {
  constexpr int NW = WR * WC;
  constexpr int AI = BM / WR / 16;
  constexpr int BJ = BN / WC / 16;
  constexpr int LPA = BM / (NW * 8);
  constexpr int LPB = BN / (NW * 8);
  constexpr int LPS = LPA + LPB;
  constexpr int MCH = NXB / 8;               // M-blocks per XCD chunk
  __shared__ __align__(16) bf16_t As[(DBUF + 1) * BM * 64];
  __shared__ __align__(16) bf16_t Bs[(DBUF + 1) * BN * 64];
  const int tid = threadIdx.x;
  const int lane = tid & 63, wid = tid >> 6;
  const int bid = blockIdx.x;
  const int xcd = bid & 7, li = bid >> 3;
  const int m0 = (xcd * MCH + li % MCH) * BM;
  const int n0 = (li / MCH) * BN;
  const int wr = wid / WC, wc = wid % WC;
  const int l15 = lane & 15, lg = lane >> 4;
  const int srow = lane >> 3;
  const int scolx = ((lane & 7) ^ srow) * 8;   // pre-swizzled source column

  f32x4 acc[AI][BJ];
#pragma unroll
  for (int i = 0; i < AI; i++)
#pragma unroll
    for (int j = 0; j < BJ; j++) acc[i][j] = f32x4{0.f, 0.f, 0.f, 0.f};

  const bf16_t* Ag = A + (size_t)(m0 + wid * (BM / NW) + srow) * K + scolx;
  const bf16_t* Bg = Bt + (size_t)(n0 + wid * (BN / NW) + srow) * K + scolx;

  auto STG = [&](int buf, int k0) {
#pragma unroll
    for (int i = 0; i < LPA; i++)
      gload_lds16(Ag + (size_t)i * 8 * K + k0,
                  As + buf * (BM * 64) + wid * (BM / NW) * 64 + i * 8 * 64);
#pragma unroll
    for (int i = 0; i < LPB; i++)
      gload_lds16(Bg + (size_t)i * 8 * K + k0,
                  Bs + buf * (BN * 64) + wid * (BN / NW) * 64 + i * 8 * 64);
  };

  auto CMP = [&](int buf) {
    const bf16_t* AsB = As + buf * (BM * 64);
    const bf16_t* BsB = Bs + buf * (BN * 64);
#pragma unroll
    for (int ks = 0; ks < 2; ks++) {
      const int c2 = ks * 64 + lg * 16;
      bf16x8 af[AI], bfv[BJ];
#pragma unroll
      for (int i = 0; i < AI; i++)
        af[i] = lds_frag(AsB, wr * (BM / WR) + i * 16 + l15, c2);
#pragma unroll
      for (int j = 0; j < BJ; j++)
        bfv[j] = lds_frag(BsB, wc * (BN / WC) + j * 16 + l15, c2);
#pragma unroll
      for (int i = 0; i < AI; i++)
#pragma unroll
        for (int j = 0; j < BJ; j++)
          acc[i][j] = MFMA_BF16(af[i], bfv[j], acc[i][j], 0, 0, 0);
    }
  };

  if constexpr (DBUF) {
    STG(0, 0);
    const int NK = K >> 6;
#pragma unroll 2
    for (int t = 0; t < NK; t++) {
      const int buf = t & 1;
      __syncthreads();                 // CMP(t-1) reads of buf^1 done before overwrite
      if (t + 1 < NK) {
        STG(buf ^ 1, (t + 1) << 6);
        wait_vmcnt<LPS>();             // tile t's loads landed (t+1's still in flight)
      } else {
        wait_vmcnt<0>();
      }
      CMP(buf);
    }
  } else {
    for (int k0 = 0; k0 < K; k0 += 64) {
      __syncthreads();
      STG(0, k0);
      wait_vmcnt<0>();
      __syncthreads();
      CMP(0);
    }
  }

  const int r0 = m0 + wr * (BM / WR) + (lg << 2);
  const int c0 = n0 + wc * (BN / WC) + l15;
#pragma unroll
  for (int j = 0; j < BJ; j++) {
    const int col = c0 + j * 16;
    const float bvc = BIASROW ? 0.f : bias[col];
#pragma unroll
    for (int i = 0; i < AI; i++) {
      const int row = r0 + i * 16;
#pragma unroll
      for (int r = 0; r < 4; r++) {
        float v = acc[i][j][r] + (BIASROW ? bias[row + r] : bvc);
        if (RELU) v = fmaxf(v, 0.f);
        if (OUT_F32) ((float*)outp)[(size_t)(row + r) * N + col] = v;
        else         ((bf16_t*)outp)[(size_t)(row + r) * N + col] = (bf16_t)v;
      }
    }
  }
}

// ---------------- flash attention: 8 waves, QBLK=128, static softmax ----------------
// 3-buffer K/V, 1 barrier/tile, counted vmcnt(2), hw exp2.
__global__ __launch_bounds__(512) void attn_k(const bf16_t* __restrict__ Q,
                                              const bf16_t* __restrict__ Kp,
                                              const bf16_t* __restrict__ Vt,
                                              const float* __restrict__ btabS,
                                              const float* __restrict__ relb,
                                              bf16_t* __restrict__ ctx) {
  __shared__ __align__(16) bf16_t Ks[3][64 * 64];
  __shared__ __align__(16) bf16_t Vs[3][64 * 64];
  __shared__ __align__(16) bf16_t Ps[8][16 * 64];
  const int tid = threadIdx.x;
  const int lane = tid & 63, wid = tid >> 6;
  const int bid = blockIdx.x;
  const int xcd = bid & 7, tt = bid >> 3;
  const int qb = tt & 15, bh = (tt >> 4) * 8 + xcd;
  const int q0 = qb * 128;
  const int bb = bh >> 3, h = bh & 7;
  const size_t qkbase = (size_t)bb * 2048 * 1024;
  const size_t cbase = (size_t)bb * 2048 * 512;
  const int hc = h * 64;
  const int l15 = lane & 15, lg = lane >> 4;
  const int srow = lane >> 3;
  const int scolx = ((lane & 7) ^ srow) * 8;

  const bf16_t* qp = Q + qkbase + (size_t)(q0 + wid * 16 + l15) * 1024 + hc + lg * 8;
  bf16x8 qf0 = *(const bf16x8*)qp;
  bf16x8 qf1 = *(const bf16x8*)(qp + 32);

  const float SCL = 0.125f * 1.44269504088896f;
  const float* bt = btabS + (size_t)h * 4095 + 2047;
  const float cbp = relb[h * 32 + 15] * SCL;
  const float cbn = relb[h * 32 + 31] * SCL;

  float lrow = 0.f;                         // lane-local partial row sum
  f32x4 acc[4];
#pragma unroll
  for (int dn = 0; dn < 4; dn++) acc[dn] = f32x4{0.f, 0.f, 0.f, 0.f};
  char* pw = (char*)&Ps[wid][0];
  const int rq = q0 + wid * 16 + l15;

  const bf16_t* kg = Kp + qkbase + (size_t)(wid * 8 + srow) * 1024 + hc + scolx;
  const bf16_t* vg = Vt + (size_t)(hc + wid * 8 + srow) * 8192 + bb * 2048 + scolx;

#define STAGE(bufp, kv0)                                              \
  do {                                                                \
    gload_lds16(kg + (size_t)(kv0) * 1024, &Ks[bufp][wid * 8 * 64]);  \
    gload_lds16(vg + (kv0), &Vs[bufp][wid * 8 * 64]);                 \
  } while (0)

  auto TILE = [&](int t, int buf) {
    const int kv0 = t * 64;
    const bf16_t* KsB = &Ks[buf][0];
    const bf16_t* VsB = &Vs[buf][0];

    f32x4 s[4];
#pragma unroll
    for (int n = 0; n < 4; n++) s[n] = f32x4{0.f, 0.f, 0.f, 0.f};
    __builtin_amdgcn_s_setprio(1);
#pragma unroll
    for (int ks = 0; ks < 2; ks++) {
      bf16x8 qf = ks ? qf1 : qf0;
      const int c2 = ks * 64 + lg * 16;
#pragma unroll
      for (int n = 0; n < 4; n++) {
        bf16x8 kf = lds_frag(KsB, n * 16 + l15, c2);
        s[n] = MFMA_BF16(kf, qf, s[n], 0, 0, 0);
      }
    }
    __builtin_amdgcn_s_setprio(0);

    float lg2[4][4];
    const bool farp = (q0 - kv0) >= 192;   // min rel = q0-kv0-63 >= 129
    const bool farn = (kv0 - q0) >= 256;   // max rel = q0+127-kv0 <= -129
    if (farp || farn) {
      const float cb = farp ? cbp : cbn;
#pragma unroll
      for (int n = 0; n < 4; n++)
#pragma unroll
        for (int r = 0; r < 4; r++) lg2[n][r] = s[n][r] * SCL + cb;
    } else {
#pragma unroll
      for (int n = 0; n < 4; n++) {
        const float* btn = bt + (rq - kv0 - n * 16 - lg * 4);
#pragma unroll
        for (int r = 0; r < 4; r++) lg2[n][r] = s[n][r] * SCL + btn[-r];
      }
    }

#pragma unroll
    for (int n = 0; n < 4; n++) {
      float p0 = __builtin_amdgcn_exp2f(lg2[n][0]);
      float p1 = __builtin_amdgcn_exp2f(lg2[n][1]);
      float p2 = __builtin_amdgcn_exp2f(lg2[n][2]);
      float p3 = __builtin_amdgcn_exp2f(lg2[n][3]);
      lrow += (p0 + p1) + (p2 + p3);
      unsigned w0, w1;
      asm("v_cvt_pk_bf16_f32 %0, %1, %2" : "=v"(w0) : "v"(p0), "v"(p1));
      asm("v_cvt_pk_bf16_f32 %0, %1, %2" : "=v"(w1) : "v"(p2), "v"(p3));
      uint2 wv = {w0, w1};
      *(uint2*)(pw + (((l15 << 7) + n * 32 + (lg >> 1) * 16 + (lg & 1) * 8)
                      ^ ((l15 & 7) << 4))) = wv;
    }

    asm volatile("s_waitcnt lgkmcnt(0)" ::: "memory");
    __builtin_amdgcn_sched_barrier(0);

    __builtin_amdgcn_s_setprio(1);
#pragma unroll
    for (int ks = 0; ks < 2; ks++) {
      const int c2 = ks * 64 + lg * 16;
      bf16x8 pa = *(const bf16x8*)(pw + (((l15 << 7) + ks * 64 + (lg >> 1) * 32 + (lg & 1) * 16)
                                         ^ ((l15 & 7) << 4)));
#pragma unroll
      for (int dn = 0; dn < 4; dn++) {
        bf16x8 vf = lds_frag(VsB, dn * 16 + l15, c2);
        acc[dn] = MFMA_BF16(pa, vf, acc[dn], 0, 0, 0);
      }
    }
    __builtin_amdgcn_s_setprio(0);
  };

  // prologue: 2 tiles in flight (depth-2); 3-buffer rotation, 1 barrier/tile
  STAGE(0, 0);
  STAGE(1, 64);

  int cur = 0, nx2 = 2;
  for (int t = 0; t < 31; t++) {
    wait_vmcnt<2>();
    __syncthreads();
    TILE(t, cur);
    if (t < 30) STAGE(nx2, (t + 2) * 64);
    cur = (cur == 2) ? 0 : cur + 1;
    nx2 = (nx2 == 2) ? 0 : nx2 + 1;
  }
  wait_vmcnt<0>();
  __syncthreads();
  TILE(31, cur);
#undef STAGE

  // reduce lane-local partial sums once
  lrow += __shfl_xor(lrow, 16, 64);
  lrow += __shfl_xor(lrow, 32, 64);

  float li0 = __shfl(lrow, (lg << 2) + 0, 64);
  float li1 = __shfl(lrow, (lg << 2) + 1, 64);
  float li2 = __shfl(lrow, (lg << 2) + 2, 64);
  float li3 = __shfl(lrow, (lg << 2) + 3, 64);
  float inv[4] = {1.f / li0, 1.f / li1, 1.f / li2, 1.f / li3};
  const int qr0 = q0 + wid * 16 + (lg << 2);
#pragma unroll
  for (int dn = 0; dn < 4; dn++)
#pragma unroll
    for (int r = 0; r < 4; r++)
      ctx[cbase + (size_t)(qr0 + r) * 512 + hc + dn * 16 + l15] = (bf16_t)(acc[dn][r] * inv[r]);
}

// ---------------- residual + LayerNorm (bf16 inputs; optional f32/bf16 outputs) ----------------
__global__ __launch_bounds__(256) void lnres_k(const bf16_t* __restrict__ a,
                                               const bf16_t* __restrict__ bsrc,
                                               const float* __restrict__ sc,
                                               const float* __restrict__ bi,
                                               float* __restrict__ outf,
                                               bf16_t* __restrict__ outb) {
  int row = blockIdx.x * 4 + (threadIdx.x >> 6);
  int lane = threadIdx.x & 63;
  size_t base = (size_t)row * 512 + lane * 8;
  bf16x8 av8 = *(const bf16x8*)(a + base);
  bf16x8 bv8 = *(const bf16x8*)(bsrc + base);
  float v[8];
#pragma unroll
  for (int j = 0; j < 8; j++) v[j] = (float)av8[j] + (float)bv8[j];
  float s1 = 0.f, s2 = 0.f;
#pragma unroll
  for (int j = 0; j < 8; j++) { s1 += v[j]; s2 += v[j] * v[j]; }
#pragma unroll
  for (int off = 1; off < 64; off <<= 1) {
    s1 += __shfl_xor(s1, off, 64);
    s2 += __shfl_xor(s2, off, 64);
  }
  float mu = s1 * (1.f / 512.f);
  float var = s2 * (1.f / 512.f) - mu * mu;
  float rstd = rsqrtf(var + 1e-6f);
  int c = lane * 8;
  float4 sc0 = *(const float4*)(sc + c), sc1 = *(const float4*)(sc + c + 4);
  float4 bi0 = *(const float4*)(bi + c), bi1 = *(const float4*)(bi + c + 4);
  float scv[8] = {sc0.x, sc0.y, sc0.z, sc0.w, sc1.x, sc1.y, sc1.z, sc1.w};
  float biv[8] = {bi0.x, bi0.y, bi0.z, bi0.w, bi1.x, bi1.y, bi1.z, bi1.w};
  float o[8];
#pragma unroll
  for (int j = 0; j < 8; j++) o[j] = (v[j] - mu) * rstd * scv[j] + biv[j];
  if (outf) {
    *(float4*)(outf + base) = make_float4(o[0], o[1], o[2], o[3]);
    *(float4*)(outf + base + 4) = make_float4(o[4], o[5], o[6], o[7]);
  }
  if (outb) {
    bf16x8 ob = {(bf16_t)o[0], (bf16_t)o[1], (bf16_t)o[2], (bf16_t)o[3],
                 (bf16_t)o[4], (bf16_t)o[5], (bf16_t)o[6], (bf16_t)o[7]};
    *(bf16x8*)(outb + base) = ob;
  }
}

// ---------------- host launcher ----------------
extern "C" void kernel_launch(void* const* d_in, const int* in_sizes, int n_in,
                              void* d_out, int out_size, void* d_ws, size_t ws_size,
                              hipStream_t stream) {
  const float* x    = (const float*)d_in[0];
  const float* Wq   = (const float*)d_in[1];
  const float* bq   = (const float*)d_in[2];
  const float* Wk   = (const float*)d_in[3];
  const float* bk   = (const float*)d_in[4];
  const float* Wv   = (const float*)d_in[5];
  const float* bv   = (const float*)d_in[6];
  const float* Wo   = (const float*)d_in[7];
  const float* bo   = (const float*)d_in[8];
  const float* relb = (const float*)d_in[9];
  const float* W1   = (const float*)d_in[10];
  const float* b1   = (const float*)d_in[11];
  const float* W2   = (const float*)d_in[12];
  const float* b2   = (const float*)d_in[13];
  const float* ln1s = (const float*)d_in[14];
  const float* ln1b = (const float*)d_in[15];
  const float* ln2s = (const float*)d_in[16];
  const float* ln2b = (const float*)d_in[17];

  char* w = (char*)d_ws;
  bf16_t* xb    = (bf16_t*)(w + 0);          //  8 MB [8192][512]; read until lnres1
  bf16_t* qk    = (bf16_t*)(w + 8388608);    // 16 MB [8192][1024]; dead after attn
  bf16_t* tmpb  = (bf16_t*)(w + 8388608);    //  8 MB (Wo out bf16; overlays dead qk)
  bf16_t* vtg   = (bf16_t*)(w + 25165824);   //  8 MB [512][8192]; dead after attn
  bf16_t* ctxb  = (bf16_t*)(w + 33554432);   //  8 MB; dead after Wo
  bf16_t* tmpb2 = (bf16_t*)(w + 33554432);   //  8 MB (FFN2 out bf16; overlays dead ctxb)
  bf16_t* x1b   = (bf16_t*)(w + 50331648);   //  8 MB (LN1 out bf16)
  bf16_t* WqkT  = (bf16_t*)(w + 58720256);   //  1 MB [1024][512]
  bf16_t* WvT   = (bf16_t*)(w + 59768832);   // 0.5 MB
  bf16_t* WoT   = (bf16_t*)(w + 60293120);   // 0.5 MB
  bf16_t* W1T   = (bf16_t*)(w + 60817408);   //  2 MB [2048][512]
  bf16_t* W2T   = (bf16_t*)(w + 62914560);   //  2 MB [512][2048]
  float*  btab  = (float*)(w + 65011712);    // 128 KB
  float*  bqk   = (float*)(w + 65273856);    //  4 KB
  bf16_t* ffh   = (bf16_t*)(w + 67108864);   // 32 MB [8192][2048]

  // single merged prep launch
  prep_k<<<4996, 256, 0, stream>>>(x, xb, Wq, Wk, Wv, Wo, W1, W2,
                                   WqkT, WvT, WoT, W1T, W2T,
                                   relb, btab, bq, bk, bqk);

  // QK projection [8192][1024]: 128x128, 4 waves, dbuf-1barrier, XCD-swizzled
  gemm_k<128, 128, 2, 2, 64, 0, 0, 0, 1><<<512, 256, 0, stream>>>(xb, WqkT, bqk, qk, 8192, 1024, 512);
  // V^T projection: 64x128, dbuf-1barrier, XCD-swizzled
  gemm_k<64, 128, 1, 4, 8, 0, 0, 1, 1><<<512, 256, 0, stream>>>(WvT, xb, bv, vtg, 512, 8192, 512);

  // attention: 8 waves, QBLK=128, grid 512 XCD-swizzled, static softmax, hw exp2
  attn_k<<<512, 512, 0, stream>>>(qk, qk + 512, vtg, btab, relb, ctxb);

  // Wo (bf16 out): 64x128 dbuf-1barrier
  gemm_k<64, 128, 1, 4, 128, 0, 0, 0, 1><<<512, 256, 0, stream>>>(ctxb, WoT, bo, tmpb, 8192, 512, 512);
  lnres_k<<<2048, 256, 0, stream>>>(xb, tmpb, ln1s, ln1b, (float*)nullptr, x1b);

  // FFN1: 128x128 dbuf-1barrier
  gemm_k<128, 128, 2, 2, 64, 0, 1, 0, 1><<<1024, 256, 0, stream>>>(x1b, W1T, b1, ffh, 8192, 2048, 512);
  // FFN2: 64x128 dbuf-1barrier
  gemm_k<64, 128, 1, 4, 128, 0, 0, 0, 1><<<512, 256, 0, stream>>>(ffh, W2T, b2, tmpb2, 8192, 512, 2048);
  lnres_k<<<2048, 256, 0, stream>>>(x1b, tmpb2, ln2s, ln2b, (float*)d_out, (bf16_t*)nullptr);
}